// Round 5
// baseline (197.418 us; speedup 1.0000x reference)
//
#include <hip/hip_runtime.h>
#include <stdint.h>

// B=128, K_fc=32 -> 4096 rows, F=2048, K_LIST={64,128,256,512}, TAU=1, EPS=1e-20.
// Output = M_hard exactly (straight-through term is numerically zero forward).
//
// R5: two-kernel split.
//  A (select): per-row 13-bit radix histogram select (R4 logic), writes 4 u64
//    thresholds per row to d_ws. Read-bound, no 134 MB store in its shadow.
//  B (mask): pure streaming — recompute bit-identical keys (same logf code ->
//    same bits), compare vs row thresholds, nontemporal float4 stores.
//    No LDS, no barriers -> runs at the HBM write ceiling.

#define F_DIM 2048
#define NT    256
#define EPT   8
#define KSB   4
#define CAP   256

typedef float f32x4 __attribute__((ext_vector_type(4)));

// Monotonic descending key: kd(a) < kd(b)  <=>  a > b (total order on f32)
__device__ __forceinline__ uint32_t f32_desc_key(float x) {
    uint32_t u = __float_as_uint(x);
    uint32_t ka = (u & 0x80000000u) ? ~u : (u | 0x80000000u);
    return ~ka;
}

// -------------------- Kernel A: per-row threshold selection --------------------
__global__ __launch_bounds__(NT)
void hsb_select(const float* __restrict__ scores,
                const float* __restrict__ uin,
                unsigned long long* __restrict__ thr) {
    const int row  = blockIdx.x;
    const int t    = threadIdx.x;
    const int lane = t & 63;
    const int wave = t >> 6;

    __shared__ uint32_t hist[4096];               // 8192 u16 bins packed
    uint32_t (*cand)[CAP] = (uint32_t (*)[CAP])hist;
    __shared__ uint32_t waveSum[4];
    __shared__ uint32_t selBin[KSB];
    __shared__ uint32_t selRem[KSB];
    __shared__ uint32_t selCnt[KSB];
    __shared__ uint32_t selThr[KSB];

    const int base = row * F_DIM;
    const float4* s4 = (const float4*)(scores + base);
    const float4* u4 = (const float4*)(uin + base);

    float4 sv0 = s4[t];       float4 uv0 = u4[t];
    float4 sv1 = s4[t + NT];  float4 uv1 = u4[t + NT];
    {
        uint4 z = {0u, 0u, 0u, 0u};
        #pragma unroll
        for (int i = 0; i < 4; ++i) ((uint4*)hist)[t + i * NT] = z;
    }

    unsigned long long key[EPT];
    {
        float ss[EPT] = {sv0.x, sv0.y, sv0.z, sv0.w, sv1.x, sv1.y, sv1.z, sv1.w};
        float uu[EPT] = {uv0.x, uv0.y, uv0.z, uv0.w, uv1.x, uv1.y, uv1.z, uv1.w};
        #pragma unroll
        for (int e = 0; e < EPT; ++e) {
            float inner = -logf(uu[e] + 1e-20f);   // byte-identical reference math
            float g     = -logf(inner + 1e-20f);
            float p     = ss[e] + g;
            uint32_t idx = (uint32_t)((e < 4) ? (4 * t + e) : (1024 + 4 * t + (e - 4)));
            key[e] = (((unsigned long long)f32_desc_key(p)) << 11) |
                     (unsigned long long)idx;
        }
    }
    __syncthreads();

    #pragma unroll
    for (int e = 0; e < EPT; ++e) {
        uint32_t dg = (uint32_t)(key[e] >> 30);
        atomicAdd(&hist[dg >> 1], 1u << ((dg & 1u) << 4));
    }
    __syncthreads();

    uint32_t w16[16];
    {
        uint4 a = ((uint4*)hist)[4 * t + 0];
        uint4 b = ((uint4*)hist)[4 * t + 1];
        uint4 c = ((uint4*)hist)[4 * t + 2];
        uint4 d = ((uint4*)hist)[4 * t + 3];
        w16[0]=a.x; w16[1]=a.y; w16[2]=a.z;  w16[3]=a.w;
        w16[4]=b.x; w16[5]=b.y; w16[6]=b.z;  w16[7]=b.w;
        w16[8]=c.x; w16[9]=c.y; w16[10]=c.z; w16[11]=c.w;
        w16[12]=d.x; w16[13]=d.y; w16[14]=d.z; w16[15]=d.w;
    }
    uint32_t run = 0;
    #pragma unroll
    for (int i = 0; i < 16; ++i) run += (w16[i] & 0xFFFFu) + (w16[i] >> 16);
    uint32_t v = run;
    #pragma unroll
    for (int d = 1; d < 64; d <<= 1) {
        uint32_t n = __shfl_up(v, (unsigned)d, 64);
        if (lane >= d) v += n;
    }
    if (lane == 63) waveSum[wave] = v;
    __syncthreads();
    uint32_t woff = 0;
    #pragma unroll
    for (int w = 0; w < 4; ++w) woff += (w < wave) ? waveSum[w] : 0u;
    const uint32_t thrOff = woff + v - run;

    if (t < KSB) selCnt[t] = 0;
    {
        const uint32_t Ks[KSB] = {64u, 128u, 256u, 512u};
        #pragma unroll
        for (int s = 0; s < KSB; ++s) {
            uint32_t r = Ks[s] - 1u;
            if (r >= thrOff && r < thrOff + run) {
                uint32_t acc = thrOff;
                #pragma unroll
                for (int i = 0; i < 16; ++i) {
                    uint32_t c0 = w16[i] & 0xFFFFu, c1 = w16[i] >> 16;
                    if (r >= acc && r < acc + c0) { selBin[s] = 32u*t + 2u*i;      selRem[s] = r - acc; }
                    acc += c0;
                    if (r >= acc && r < acc + c1) { selBin[s] = 32u*t + 2u*i + 1u; selRem[s] = r - acc; }
                    acc += c1;
                }
            }
        }
    }
    __syncthreads();

    {
        const uint32_t b0 = selBin[0], b1 = selBin[1], b2 = selBin[2], b3 = selBin[3];
        #pragma unroll
        for (int e = 0; e < EPT; ++e) {
            uint32_t dg = (uint32_t)(key[e] >> 30);
            uint32_t lo = (uint32_t)key[e] & 0x3FFFFFFFu;
            if (dg == b0) { uint32_t p = atomicAdd(&selCnt[0], 1u); if (p < CAP) cand[0][p] = lo; }
            if (dg == b1) { uint32_t p = atomicAdd(&selCnt[1], 1u); if (p < CAP) cand[1][p] = lo; }
            if (dg == b2) { uint32_t p = atomicAdd(&selCnt[2], 1u); if (p < CAP) cand[2][p] = lo; }
            if (dg == b3) { uint32_t p = atomicAdd(&selCnt[3], 1u); if (p < CAP) cand[3][p] = lo; }
        }
    }
    __syncthreads();

    {
        const int s = wave;
        const uint32_t C = min(selCnt[s], (uint32_t)CAP);
        const uint32_t r = selRem[s];
        for (uint32_t i = lane; i < C; i += 64) {
            uint32_t ci = cand[s][i];
            uint32_t cnt = 0;
            for (uint32_t j = 0; j < C; ++j) cnt += (cand[s][j] < ci);
            if (cnt == r) selThr[s] = ci;
        }
    }
    __syncthreads();

    if (t < KSB)
        thr[row * KSB + t] =
            (((unsigned long long)selBin[t]) << 30) | (unsigned long long)selThr[t];
}

// -------------------- Kernel B: streaming mask writer --------------------
// 2 blocks per row; thread t handles 4 contiguous elements of its half-row.
__global__ __launch_bounds__(NT)
void hsb_mask(const float* __restrict__ scores,
              const float* __restrict__ uin,
              const unsigned long long* __restrict__ thr,
              float* __restrict__ out) {
    const int row  = blockIdx.x >> 1;
    const int half = blockIdx.x & 1;
    const int t    = threadIdx.x;
    const int off  = half * 1024 + 4 * t;        // element offset within row

    const int base = row * F_DIM + off;
    float4 sv = *(const float4*)(scores + base);
    float4 uv = *(const float4*)(uin + base);

    // row-uniform threshold loads (compiler scalarizes; L1/L2-hit)
    const unsigned long long T0 = thr[row * KSB + 0];
    const unsigned long long T1 = thr[row * KSB + 1];
    const unsigned long long T2 = thr[row * KSB + 2];
    const unsigned long long T3 = thr[row * KSB + 3];

    float ss[4] = {sv.x, sv.y, sv.z, sv.w};
    float uu[4] = {uv.x, uv.y, uv.z, uv.w};
    f32x4 m0, m1, m2, m3;
    #pragma unroll
    for (int j = 0; j < 4; ++j) {
        float inner = -logf(uu[j] + 1e-20f);     // same code as kernel A -> same bits
        float g     = -logf(inner + 1e-20f);
        float p     = ss[j] + g;
        unsigned long long key =
            (((unsigned long long)f32_desc_key(p)) << 11) |
            (unsigned long long)(uint32_t)(off + j);
        m0[j] = (key <= T0) ? 1.0f : 0.0f;
        m1[j] = (key <= T1) ? 1.0f : 0.0f;
        m2[j] = (key <= T2) ? 1.0f : 0.0f;
        m3[j] = (key <= T3) ? 1.0f : 0.0f;
    }

    float* outrow = out + (size_t)row * (KSB * F_DIM) + off;
    __builtin_nontemporal_store(m0, (f32x4*)(outrow + 0 * F_DIM));
    __builtin_nontemporal_store(m1, (f32x4*)(outrow + 1 * F_DIM));
    __builtin_nontemporal_store(m2, (f32x4*)(outrow + 2 * F_DIM));
    __builtin_nontemporal_store(m3, (f32x4*)(outrow + 3 * F_DIM));
}

extern "C" void kernel_launch(void* const* d_in, const int* in_sizes, int n_in,
                              void* d_out, int out_size, void* d_ws, size_t ws_size,
                              hipStream_t stream) {
    const float* scores = (const float*)d_in[0];
    const float* u      = (const float*)d_in[1];
    float* out          = (float*)d_out;
    unsigned long long* thr = (unsigned long long*)d_ws;  // 4096*4*8 = 128 KB
    const int rows = in_sizes[0] / F_DIM;  // 4096
    hsb_select<<<dim3(rows),     dim3(NT), 0, stream>>>(scores, u, thr);
    hsb_mask  <<<dim3(rows * 2), dim3(NT), 0, stream>>>(scores, u, thr, out);
}

// Round 6
// 195.782 us; speedup vs baseline: 1.0084x; 1.0084x over previous
//
#include <hip/hip_runtime.h>
#include <stdint.h>

// B=128, K_fc=32 -> 4096 rows, F=2048, K_LIST={64,128,256,512}, TAU=1, EPS=1e-20.
// Output = M_hard exactly (straight-through term is numerically zero forward).
//
// R6: monolithic select (R4 logic: 13-bit packed-u16 radix histogram, parallel
// scan, gated bin-find, tiny all-pairs), but 2 rows per block with a software
// pipeline: row1 loads issued before row0's select; row0's mask stores issued
// back-to-back with row1's logf-heavy key build (no barrier between) so the
// 134 MB store stream drains on the vmem pipe under the VALU work.

#define F_DIM 2048
#define NT    256
#define EPT   8
#define KSB   4
#define CAP   256
#define NR    2     // rows per block

typedef float f32x4 __attribute__((ext_vector_type(4)));

// Monotonic descending key: kd(a) < kd(b)  <=>  a > b (total order on f32)
__device__ __forceinline__ uint32_t f32_desc_key(float x) {
    uint32_t u = __float_as_uint(x);
    uint32_t ka = (u & 0x80000000u) ? ~u : (u | 0x80000000u);
    return ~ka;
}

__global__ __launch_bounds__(NT)
void hsb_kernel(const float* __restrict__ scores,
                const float* __restrict__ uin,
                float* __restrict__ out) {
    const int row0 = blockIdx.x * NR;
    const int t    = threadIdx.x;
    const int lane = t & 63;
    const int wave = t >> 6;

    __shared__ uint32_t hist[4096];               // 8192 u16 bins packed (16 KB)
    uint32_t (*cand)[CAP] = (uint32_t (*)[CAP])hist;  // alias: dead after scan
    __shared__ uint32_t waveSum[4];
    __shared__ uint32_t selBin[KSB];
    __shared__ uint32_t selRem[KSB];
    __shared__ uint32_t selCnt[KSB];
    __shared__ uint32_t selThr[KSB];

    // ---- prefetch row0 ----
    const float4* s4 = (const float4*)(scores + row0 * F_DIM);
    const float4* u4 = (const float4*)(uin    + row0 * F_DIM);
    float4 svA0 = s4[t];       float4 uvA0 = u4[t];
    float4 svA1 = s4[t + NT];  float4 uvA1 = u4[t + NT];

    // zero hist while row0 loads are in flight
    {
        uint4 z = {0u, 0u, 0u, 0u};
        #pragma unroll
        for (int i = 0; i < 4; ++i) ((uint4*)hist)[t + i * NT] = z;
    }

    float4 svB0, uvB0, svB1, uvB1;   // row1 prefetch

    #pragma unroll
    for (int r = 0; r < NR; ++r) {
        const int row = row0 + r;

        // ---- build keys (VALU heavy; for r>0 this overlaps prev row's store drain) ----
        unsigned long long key[EPT];
        {
            float4 sv0 = (r == 0) ? svA0 : svB0;
            float4 uv0 = (r == 0) ? uvA0 : uvB0;
            float4 sv1 = (r == 0) ? svA1 : svB1;
            float4 uv1 = (r == 0) ? uvA1 : uvB1;
            float ss[EPT] = {sv0.x, sv0.y, sv0.z, sv0.w, sv1.x, sv1.y, sv1.z, sv1.w};
            float uu[EPT] = {uv0.x, uv0.y, uv0.z, uv0.w, uv1.x, uv1.y, uv1.z, uv1.w};
            #pragma unroll
            for (int e = 0; e < EPT; ++e) {
                float inner = -logf(uu[e] + 1e-20f);   // byte-identical reference math
                float g     = -logf(inner + 1e-20f);
                float p     = ss[e] + g;
                uint32_t idx = (uint32_t)((e < 4) ? (4 * t + e) : (1024 + 4 * t + (e - 4)));
                key[e] = (((unsigned long long)f32_desc_key(p)) << 11) |
                         (unsigned long long)idx;
            }
        }

        // ---- prefetch next row (in flight across the whole select phase) ----
        if (r + 1 < NR) {
            const float4* s4n = (const float4*)(scores + (row + 1) * F_DIM);
            const float4* u4n = (const float4*)(uin    + (row + 1) * F_DIM);
            svB0 = s4n[t];       uvB0 = u4n[t];
            svB1 = s4n[t + NT];  uvB1 = u4n[t + NT];
        }
        __syncthreads();                                       // B1 (hist zeroed)

        // ---- 13-bit histogram: digit = key >> 30; packed u16 counts ----
        #pragma unroll
        for (int e = 0; e < EPT; ++e) {
            uint32_t dg = (uint32_t)(key[e] >> 30);
            atomicAdd(&hist[dg >> 1], 1u << ((dg & 1u) << 4));
        }
        __syncthreads();                                       // B2

        // ---- parallel scan: thread t owns words 16t..16t+15 ----
        uint32_t w16[16];
        {
            uint4 a = ((uint4*)hist)[4 * t + 0];
            uint4 b = ((uint4*)hist)[4 * t + 1];
            uint4 c = ((uint4*)hist)[4 * t + 2];
            uint4 d = ((uint4*)hist)[4 * t + 3];
            w16[0]=a.x;  w16[1]=a.y;  w16[2]=a.z;  w16[3]=a.w;
            w16[4]=b.x;  w16[5]=b.y;  w16[6]=b.z;  w16[7]=b.w;
            w16[8]=c.x;  w16[9]=c.y;  w16[10]=c.z; w16[11]=c.w;
            w16[12]=d.x; w16[13]=d.y; w16[14]=d.z; w16[15]=d.w;
        }
        uint32_t run = 0;
        #pragma unroll
        for (int i = 0; i < 16; ++i) run += (w16[i] & 0xFFFFu) + (w16[i] >> 16);
        uint32_t v = run;
        #pragma unroll
        for (int d = 1; d < 64; d <<= 1) {
            uint32_t n = __shfl_up(v, (unsigned)d, 64);
            if (lane >= d) v += n;
        }
        if (lane == 63) waveSum[wave] = v;
        __syncthreads();                                       // B3
        uint32_t woff = 0;
        #pragma unroll
        for (int w = 0; w < 4; ++w) woff += (w < wave) ? waveSum[w] : 0u;
        const uint32_t thrOff = woff + v - run;

        // ---- gated bin-find ----
        if (t < KSB) selCnt[t] = 0;
        {
            const uint32_t Ks[KSB] = {64u, 128u, 256u, 512u};
            #pragma unroll
            for (int s = 0; s < KSB; ++s) {
                uint32_t rk = Ks[s] - 1u;
                if (rk >= thrOff && rk < thrOff + run) {
                    uint32_t acc = thrOff;
                    #pragma unroll
                    for (int i = 0; i < 16; ++i) {
                        uint32_t c0 = w16[i] & 0xFFFFu, c1 = w16[i] >> 16;
                        if (rk >= acc && rk < acc + c0) { selBin[s] = 32u*t + 2u*i;      selRem[s] = rk - acc; }
                        acc += c0;
                        if (rk >= acc && rk < acc + c1) { selBin[s] = 32u*t + 2u*i + 1u; selRem[s] = rk - acc; }
                        acc += c1;
                    }
                }
            }
        }
        __syncthreads();                                       // B4

        // ---- collect threshold-bin members (C ~ 5-30) ----
        {
            const uint32_t b0 = selBin[0], b1 = selBin[1], b2 = selBin[2], b3 = selBin[3];
            #pragma unroll
            for (int e = 0; e < EPT; ++e) {
                uint32_t dg = (uint32_t)(key[e] >> 30);
                uint32_t lo = (uint32_t)key[e] & 0x3FFFFFFFu;
                if (dg == b0) { uint32_t p = atomicAdd(&selCnt[0], 1u); if (p < CAP) cand[0][p] = lo; }
                if (dg == b1) { uint32_t p = atomicAdd(&selCnt[1], 1u); if (p < CAP) cand[1][p] = lo; }
                if (dg == b2) { uint32_t p = atomicAdd(&selCnt[2], 1u); if (p < CAP) cand[2][p] = lo; }
                if (dg == b3) { uint32_t p = atomicAdd(&selCnt[3], 1u); if (p < CAP) cand[3][p] = lo; }
            }
        }
        __syncthreads();                                       // B5

        // ---- tiny all-pairs rank within bin: wave s handles selector s ----
        {
            const int s = wave;
            const uint32_t C = min(selCnt[s], (uint32_t)CAP);
            const uint32_t rk = selRem[s];
            for (uint32_t i = lane; i < C; i += 64) {
                uint32_t ci = cand[s][i];
                uint32_t cnt = 0;
                for (uint32_t j = 0; j < C; ++j) cnt += (cand[s][j] < ci);
                if (cnt == rk) selThr[s] = ci;   // unique keys -> one writer
            }
        }
        __syncthreads();                                       // B6

        // ---- masks: rank < K  <=>  key <= T_K; stores drain under next key build ----
        const unsigned long long T0 = (((unsigned long long)selBin[0]) << 30) | selThr[0];
        const unsigned long long T1 = (((unsigned long long)selBin[1]) << 30) | selThr[1];
        const unsigned long long T2 = (((unsigned long long)selBin[2]) << 30) | selThr[2];
        const unsigned long long T3 = (((unsigned long long)selBin[3]) << 30) | selThr[3];
        float* outrow = out + (size_t)row * (KSB * F_DIM);
        #pragma unroll
        for (int h = 0; h < 2; ++h) {
            f32x4 m0, m1, m2, m3;
            #pragma unroll
            for (int j = 0; j < 4; ++j) {
                unsigned long long k = key[h * 4 + j];
                m0[j] = (k <= T0) ? 1.0f : 0.0f;
                m1[j] = (k <= T1) ? 1.0f : 0.0f;
                m2[j] = (k <= T2) ? 1.0f : 0.0f;
                m3[j] = (k <= T3) ? 1.0f : 0.0f;
            }
            const int off = h * 1024 + 4 * t;
            __builtin_nontemporal_store(m0, (f32x4*)(outrow + 0 * F_DIM + off));
            __builtin_nontemporal_store(m1, (f32x4*)(outrow + 1 * F_DIM + off));
            __builtin_nontemporal_store(m2, (f32x4*)(outrow + 2 * F_DIM + off));
            __builtin_nontemporal_store(m3, (f32x4*)(outrow + 3 * F_DIM + off));
        }

        // ---- re-zero hist for next row (cand alias dead after B6) ----
        if (r + 1 < NR) {
            uint4 z = {0u, 0u, 0u, 0u};
            #pragma unroll
            for (int i = 0; i < 4; ++i) ((uint4*)hist)[t + i * NT] = z;
        }
    }
}

extern "C" void kernel_launch(void* const* d_in, const int* in_sizes, int n_in,
                              void* d_out, int out_size, void* d_ws, size_t ws_size,
                              hipStream_t stream) {
    const float* scores = (const float*)d_in[0];
    const float* u      = (const float*)d_in[1];
    float* out          = (float*)d_out;
    const int rows = in_sizes[0] / F_DIM;  // 4096
    hsb_kernel<<<dim3(rows / NR), dim3(NT), 0, stream>>>(scores, u, out);
}